// Round 2
// baseline (3160.674 us; speedup 1.0000x reference)
//
#include <hip/hip_runtime.h>
#include <hip/hip_bf16.h>
#include <math.h>

typedef short v8s __attribute__((ext_vector_type(8)));
typedef float v4f __attribute__((ext_vector_type(4)));
typedef unsigned short u16;

#define THRESH_EPS 1e-6f

__device__ __forceinline__ float b2f(u16 u) {
    union { unsigned int i; float f; } v; v.i = ((unsigned int)u) << 16; return v.f;
}
__device__ __forceinline__ u16 f2b(float f) {
    union { float f; unsigned int i; } v; v.f = f;
    unsigned int x = v.i;
    return (u16)((x + 0x7fffu + ((x >> 16) & 1u)) >> 16);
}
__device__ __forceinline__ float sigm(float x) { return 1.0f / (1.0f + __expf(-x)); }
__device__ __forceinline__ float tanh_(float x) { return 1.0f - 2.0f / (__expf(2.0f * x) + 1.0f); }

// Coherent (write-through, sc0 sc1) store of one bf16 value: visible at the
// device coherence point once vmcnt retires, with NO cache-maintenance insts.
__device__ __forceinline__ void st_coh(u16* p, u16 v) {
    __hip_atomic_store(p, v, __ATOMIC_RELAXED, __HIP_MEMORY_SCOPE_SYSTEM);
}

// Fence-free grid barrier: h-data already coherent via st_coh; vmcnt(0)
// guarantees those stores reached the coherence point; counter ops are
// RELAXED (no buffer_wbl2 / buffer_inv tag-walks — the 19us/step stall).
__device__ __forceinline__ void chain_bar(unsigned* cnt, unsigned target) {
    asm volatile("s_waitcnt vmcnt(0)" ::: "memory");
    __syncthreads();
    if (threadIdx.x == 0) {
        __hip_atomic_fetch_add(cnt, 1u, __ATOMIC_RELAXED, __HIP_MEMORY_SCOPE_AGENT);
        while (__hip_atomic_load(cnt, __ATOMIC_RELAXED, __HIP_MEMORY_SCOPE_AGENT) < target)
            __builtin_amdgcn_s_sleep(2);
    }
    __syncthreads();
}

// ---------------------------------------------------------------------------
// Weight conversion: f32 -> bf16 pool. 12 weight matrices, 2048 elems/block.
// ---------------------------------------------------------------------------
struct CvtTab { const float* src[12]; size_t dst_off[12]; int blk_end[12]; };

__global__ void convert_weights_kernel(CvtTab t, u16* __restrict__ pool)
{
    int b = blockIdx.x;
    int i = 0, start = 0;
    while (b >= t.blk_end[i]) { start = t.blk_end[i]; i++; }
    int local = b - start;
    const float* s = t.src[i] + (size_t)local * 2048 + threadIdx.x * 8;
    u16* d = pool + t.dst_off[i] + (size_t)local * 2048 + threadIdx.x * 8;
    float4 x0 = *(const float4*)s, x1 = *(const float4*)(s + 4);
    v8s o;
    o[0] = (short)f2b(x0.x); o[1] = (short)f2b(x0.y);
    o[2] = (short)f2b(x0.z); o[3] = (short)f2b(x0.w);
    o[4] = (short)f2b(x1.x); o[5] = (short)f2b(x1.y);
    o[6] = (short)f2b(x1.z); o[7] = (short)f2b(x1.w);
    *(v8s*)d = o;
}

// ---------------------------------------------------------------------------
// Generic GEMM: C[M,N] = act(A[M,K] @ W[N,K]^T + bias)
// A: bf16 (pad cols beyond Kreal must be zero). W: bf16, ldw = Kreal.
// OUT_F32: 0 -> bf16 out, 1 -> f32 out.  ACT: 0 none, 1 threshold(1e-6)
// tile 128x128, BK=64, 256 threads (4 waves 2x2), XOR-swizzled LDS
// ---------------------------------------------------------------------------
template<int OUT_F32, int ACT>
__global__ __launch_bounds__(256, 2) void gemm_kernel(
    const u16* __restrict__ A, int lda, int M,
    const u16* __restrict__ W, int ldw, int N,
    int Kreal, int Kloop,
    const float* __restrict__ bias,
    void* __restrict__ Cout, int ldc)
{
    __shared__ u16 sA[128 * 64];
    __shared__ u16 sB[128 * 64];
    const int tid = threadIdx.x;
    const int m0 = blockIdx.y * 128, n0 = blockIdx.x * 128;
    const int w = tid >> 6, l = tid & 63, lr = l & 15, q = l >> 4;
    const int wm = w & 1, wn = w >> 1;

    v4f acc[4][4];
#pragma unroll
    for (int a = 0; a < 4; a++)
#pragma unroll
        for (int b = 0; b < 4; b++) acc[a][b] = (v4f){0.f, 0.f, 0.f, 0.f};

    for (int kk = 0; kk < Kloop; kk += 64) {
#pragma unroll
        for (int it = 0; it < 4; it++) {
            int cid = it * 256 + tid;
            int r = cid >> 3, j = cid & 7, p = j ^ (r & 7);
            {
                int rm = m0 + r; if (rm > M - 1) rm = M - 1;
                v8s va = *(const v8s*)(A + (size_t)rm * lda + kk + j * 8);
                *(v8s*)(sA + r * 64 + p * 8) = va;
            }
            {
                int rn = n0 + r; if (rn > N - 1) rn = N - 1;
                int kc = kk + j * 8; if (kc + 8 > Kreal) kc = Kreal - 8;
                v8s vb = *(const v8s*)(W + (size_t)rn * ldw + kc);
                *(v8s*)(sB + r * 64 + p * 8) = vb;
            }
        }
        __syncthreads();
#pragma unroll
        for (int ks = 0; ks < 2; ks++) {
            v8s af[4], bfr[4];
#pragma unroll
            for (int mt = 0; mt < 4; mt++) {
                int r = wm * 64 + mt * 16 + lr;
                int j = ks * 4 + q, p = j ^ (r & 7);
                af[mt] = *(const v8s*)(sA + r * 64 + p * 8);
            }
#pragma unroll
            for (int nt = 0; nt < 4; nt++) {
                int r = wn * 64 + nt * 16 + lr;
                int j = ks * 4 + q, p = j ^ (r & 7);
                bfr[nt] = *(const v8s*)(sB + r * 64 + p * 8);
            }
#pragma unroll
            for (int mt = 0; mt < 4; mt++)
#pragma unroll
                for (int nt = 0; nt < 4; nt++)
                    acc[mt][nt] = __builtin_amdgcn_mfma_f32_16x16x32_bf16(
                        af[mt], bfr[nt], acc[mt][nt], 0, 0, 0);
        }
        __syncthreads();
    }

#pragma unroll
    for (int nt = 0; nt < 4; nt++) {
        int n = n0 + wn * 64 + nt * 16 + lr;
        if (n >= N) continue;
        float bv = bias[n];
#pragma unroll
        for (int mt = 0; mt < 4; mt++) {
#pragma unroll
            for (int i = 0; i < 4; i++) {
                int m = m0 + wm * 64 + mt * 16 + q * 4 + i;
                if (m >= M) continue;
                float vout = acc[mt][nt][i] + bv;
                if (ACT == 1) vout = (vout > THRESH_EPS) ? vout : 0.0f;
                if (OUT_F32) ((float*)Cout)[(size_t)m * ldc + n] = vout;
                else         ((u16*)Cout)[(size_t)m * ldc + n] = f2b(vout);
            }
        }
    }
}

// ---------------------------------------------------------------------------
// Split-K GEMM for g1: A[2048, K=30000(+pad to 30016, zeroed)] @ W[512,30000]^T.
// ---------------------------------------------------------------------------
#define SK_CHUNK 3776
#define SK_SPLITS 8

__global__ __launch_bounds__(256, 2) void gemm_splitk_kernel(
    const u16* __restrict__ A, int lda,
    const u16* __restrict__ W, int ldw,
    int Kreal, int Ktot,
    float* __restrict__ Cpart)
{
    __shared__ u16 sA[128 * 64];
    __shared__ u16 sB[128 * 64];
    const int tid = threadIdx.x;
    const int m0 = blockIdx.y * 128, n0 = blockIdx.x * 128;
    const int z = blockIdx.z;
    const int kstart = z * SK_CHUNK;
    int Kl = Ktot - kstart; if (Kl > SK_CHUNK) Kl = SK_CHUNK;
    const int w = tid >> 6, l = tid & 63, lr = l & 15, q = l >> 4;
    const int wm = w & 1, wn = w >> 1;

    v4f acc[4][4];
#pragma unroll
    for (int a = 0; a < 4; a++)
#pragma unroll
        for (int b = 0; b < 4; b++) acc[a][b] = (v4f){0.f, 0.f, 0.f, 0.f};

    for (int kk = 0; kk < Kl; kk += 64) {
#pragma unroll
        for (int it = 0; it < 4; it++) {
            int cid = it * 256 + tid;
            int r = cid >> 3, j = cid & 7, p = j ^ (r & 7);
            {
                v8s va = *(const v8s*)(A + (size_t)(m0 + r) * lda + kstart + kk + j * 8);
                *(v8s*)(sA + r * 64 + p * 8) = va;
            }
            {
                int kc = kstart + kk + j * 8; if (kc + 8 > Kreal) kc = Kreal - 8;
                v8s vb = *(const v8s*)(W + (size_t)(n0 + r) * ldw + kc);
                *(v8s*)(sB + r * 64 + p * 8) = vb;
            }
        }
        __syncthreads();
#pragma unroll
        for (int ks = 0; ks < 2; ks++) {
            v8s af[4], bfr[4];
#pragma unroll
            for (int mt = 0; mt < 4; mt++) {
                int r = wm * 64 + mt * 16 + lr;
                int j = ks * 4 + q, p = j ^ (r & 7);
                af[mt] = *(const v8s*)(sA + r * 64 + p * 8);
            }
#pragma unroll
            for (int nt = 0; nt < 4; nt++) {
                int r = wn * 64 + nt * 16 + lr;
                int j = ks * 4 + q, p = j ^ (r & 7);
                bfr[nt] = *(const v8s*)(sB + r * 64 + p * 8);
            }
#pragma unroll
            for (int mt = 0; mt < 4; mt++)
#pragma unroll
                for (int nt = 0; nt < 4; nt++)
                    acc[mt][nt] = __builtin_amdgcn_mfma_f32_16x16x32_bf16(
                        af[mt], bfr[nt], acc[mt][nt], 0, 0, 0);
        }
        __syncthreads();
    }

    float* out = Cpart + (size_t)z * 1048576;
#pragma unroll
    for (int nt = 0; nt < 4; nt++) {
        int n = n0 + wn * 64 + nt * 16 + lr;
#pragma unroll
        for (int mt = 0; mt < 4; mt++) {
#pragma unroll
            for (int i = 0; i < 4; i++) {
                int m = m0 + wm * 64 + mt * 16 + q * 4 + i;
                out[(size_t)m * 512 + n] = acc[mt][nt][i];
            }
        }
    }
}

// Reduce 8 f32 partials -> thresh(+bias) -> bf16 g1 (2048 x 512)
__global__ void splitk_reduce_kernel(const float* __restrict__ part,
                                     const float* __restrict__ bias,
                                     u16* __restrict__ out)
{
    int t = blockIdx.x * 256 + threadIdx.x;
    size_t base = (size_t)t * 4;
    float4 s = *(const float4*)(part + base);
#pragma unroll
    for (int zz = 1; zz < SK_SPLITS; zz++) {
        float4 p = *(const float4*)(part + (size_t)zz * 1048576 + base);
        s.x += p.x; s.y += p.y; s.z += p.z; s.w += p.w;
    }
    int n = (int)(base & 511);
    float4 bv = *(const float4*)(bias + n);
    float o[4] = { s.x + bv.x, s.y + bv.y, s.z + bv.z, s.w + bv.w };
    u16 r0 = f2b(o[0] > THRESH_EPS ? o[0] : 0.f);
    u16 r1 = f2b(o[1] > THRESH_EPS ? o[1] : 0.f);
    u16 r2 = f2b(o[2] > THRESH_EPS ? o[2] : 0.f);
    u16 r3 = f2b(o[3] > THRESH_EPS ? o[3] : 0.f);
    out[base + 0] = r0; out[base + 1] = r1; out[base + 2] = r2; out[base + 3] = r3;
}

// ---------------------------------------------------------------------------
// Persistent GRU chain. h(f32) carried in registers; bf16 h exchanged through
// 32 per-step buffers (fresh address per step -> no stale lines anywhere),
// written with coherent write-through stores. Fence-free barrier per step.
// ---------------------------------------------------------------------------
struct GruPC {
    const u16* Whh; const float* bhh; const float* xw; // xw: (32,64,1536) f32
    u16* hb;                                            // 32 buffers of 64x512 bf16
    unsigned* cnt;                                      // this set's barrier counter
};

__global__ __launch_bounds__(256, 2) void gru_chain_kernel(GruPC s0, GruPC s1, int nblk0,
                                                           int nsteps)
{
    const GruPC S = ((int)blockIdx.x < nblk0) ? s0 : s1;
    const int cb = ((int)blockIdx.x & 7) * 64;
    const int tid = threadIdx.x, w = tid >> 6, l = tid & 63, lr = l & 15, q = l >> 4;
    const int j = cb + w * 16 + lr;
    const float br = S.bhh[j], bz = S.bhh[512 + j], bn = S.bhh[1024 + j];

    float hreg[4][4];
#pragma unroll
    for (int mt = 0; mt < 4; mt++)
#pragma unroll
        for (int i = 0; i < 4; i++) hreg[mt][i] = 0.f;

    for (int s = 0; s < nsteps; s++) {
        v4f acc[3][4];
#pragma unroll
        for (int g = 0; g < 3; g++)
#pragma unroll
            for (int mt = 0; mt < 4; mt++) acc[g][mt] = (v4f){0.f, 0.f, 0.f, 0.f};

        if (s > 0) {
            const u16* hin_b = S.hb + (size_t)(s - 1) * 32768;
            for (int kk = 0; kk < 512; kk += 32) {
                v8s a[4], b[3];
#pragma unroll
                for (int mt = 0; mt < 4; mt++)
                    a[mt] = *(const v8s*)(hin_b + (mt * 16 + lr) * 512 + kk + q * 8);
#pragma unroll
                for (int g = 0; g < 3; g++)
                    b[g] = *(const v8s*)(S.Whh + (size_t)(g * 512 + j) * 512 + kk + q * 8);
#pragma unroll
                for (int g = 0; g < 3; g++)
#pragma unroll
                    for (int mt = 0; mt < 4; mt++)
                        acc[g][mt] = __builtin_amdgcn_mfma_f32_16x16x32_bf16(a[mt], b[g], acc[g][mt], 0, 0, 0);
            }
        }

        u16* hout_b = S.hb + (size_t)s * 32768;
        const float* xws = S.xw + (size_t)s * 98304;
#pragma unroll
        for (int mt = 0; mt < 4; mt++) {
#pragma unroll
            for (int i = 0; i < 4; i++) {
                int bb = mt * 16 + q * 4 + i;
                const float* x = xws + bb * 1536;
                float r = sigm(x[j] + acc[0][mt][i] + br);
                float z = sigm(x[512 + j] + acc[1][mt][i] + bz);
                float n = tanh_(x[1024 + j] + r * (acc[2][mt][i] + bn));
                float hn = (1.f - z) * n + z * hreg[mt][i];
                hreg[mt][i] = hn;
                st_coh(hout_b + bb * 512 + j, f2b(hn));
            }
        }
        chain_bar(S.cnt, (unsigned)((s + 1) * 8));
    }
}

// ---------------------------------------------------------------------------
// Persistent LSTM chain. c in registers; h written per-step to hs[s] (fresh
// address each step) via coherent stores. Fence-free barrier per step.
// ---------------------------------------------------------------------------
__global__ __launch_bounds__(256, 2) void lstm_chain_kernel(
    const u16* __restrict__ Whh, const float* __restrict__ bhh,
    const float* __restrict__ xw_all, u16* __restrict__ hs,
    unsigned* cnt, int nsteps)
{
    const int cb = blockIdx.x * 64;
    const int tid = threadIdx.x, w = tid >> 6, l = tid & 63, lr = l & 15, q = l >> 4;
    const int j = cb + w * 16 + lr;
    const float b0 = bhh[j], b1 = bhh[512 + j], b2_ = bhh[1024 + j], b3 = bhh[1536 + j];

    float creg[4][4];
#pragma unroll
    for (int mt = 0; mt < 4; mt++)
#pragma unroll
        for (int i = 0; i < 4; i++) creg[mt][i] = 0.f;

    for (int s = 0; s < nsteps; s++) {
        v4f acc[4][4];
#pragma unroll
        for (int g = 0; g < 4; g++)
#pragma unroll
            for (int mt = 0; mt < 4; mt++) acc[g][mt] = (v4f){0.f, 0.f, 0.f, 0.f};

        if (s > 0) {
            const u16* hin = hs + (size_t)(s - 1) * 32768;
            for (int kk = 0; kk < 512; kk += 32) {
                v8s a[4], b[4];
#pragma unroll
                for (int mt = 0; mt < 4; mt++)
                    a[mt] = *(const v8s*)(hin + (mt * 16 + lr) * 512 + kk + q * 8);
#pragma unroll
                for (int g = 0; g < 4; g++)
                    b[g] = *(const v8s*)(Whh + (size_t)(g * 512 + j) * 512 + kk + q * 8);
#pragma unroll
                for (int g = 0; g < 4; g++)
#pragma unroll
                    for (int mt = 0; mt < 4; mt++)
                        acc[g][mt] = __builtin_amdgcn_mfma_f32_16x16x32_bf16(a[mt], b[g], acc[g][mt], 0, 0, 0);
            }
        }

        u16* hout = hs + (size_t)s * 32768;
        const float* xws = xw_all + (size_t)s * 131072;
#pragma unroll
        for (int mt = 0; mt < 4; mt++) {
#pragma unroll
            for (int i = 0; i < 4; i++) {
                int bb = mt * 16 + q * 4 + i;
                const float* x = xws + bb * 2048;
                float gi = sigm(x[j] + acc[0][mt][i] + b0);
                float gf = sigm(x[512 + j] + acc[1][mt][i] + b1);
                float gg = tanh_(x[1024 + j] + acc[2][mt][i] + b2_);
                float go = sigm(x[1536 + j] + acc[3][mt][i] + b3);
                float cn = gf * creg[mt][i] + gi * gg;
                creg[mt][i] = cn;
                st_coh(hout + bb * 512 + j, f2b(go * tanh_(cn)));
            }
        }
        chain_bar(cnt, (unsigned)((s + 1) * 8));
    }
}

// ---------------------------------------------------------------------------
// e1/d1: out[row, j] = thresh(W1[j, idx[row]] + b1[j]); rows = S*B = 2048
// ---------------------------------------------------------------------------
__global__ void embed_gather_kernel(const int* __restrict__ idx, const float* __restrict__ W1,
                                    const float* __restrict__ b1, u16* __restrict__ out)
{
    const int row = blockIdx.x;
    const int p = idx[row];
    for (int j = threadIdx.x; j < 512; j += 256) {
        float v = W1[(size_t)j * 30000 + p] + b1[j];
        out[(size_t)row * 512 + j] = f2b(v > THRESH_EPS ? v : 0.f);
    }
}

// dec_in[64 + row, :] = bf16(gen_emb_tab[sim[row], :]), row in [0, 1984)
__global__ void embsim_gather_kernel(const int* __restrict__ sim, const float* __restrict__ tab,
                                     u16* __restrict__ dec_in)
{
    int cid = blockIdx.x * 256 + threadIdx.x;
    int row = cid >> 6, c8 = cid & 63;
    if (row >= 1984) return;
    int p = sim[row];
    const float* s = tab + (size_t)p * 512 + c8 * 8;
    float4 x0 = *(const float4*)s, x1 = *(const float4*)(s + 4);
    v8s o;
    o[0] = (short)f2b(x0.x); o[1] = (short)f2b(x0.y);
    o[2] = (short)f2b(x0.z); o[3] = (short)f2b(x0.w);
    o[4] = (short)f2b(x1.x); o[5] = (short)f2b(x1.y);
    o[6] = (short)f2b(x1.z); o[7] = (short)f2b(x1.w);
    *(v8s*)(dec_in + (size_t)(64 + row) * 512 + c8 * 8) = o;
}

// ---------------------------------------------------------------------------
// log_softmax per row of 30000 bf16 logits (stride 30016 in pbuf).
// writes f32 out = x-m-log(S) to outp, bf16 probs = exp(x-m)/S in-place, zeroes pad
// ---------------------------------------------------------------------------
__global__ __launch_bounds__(256, 2) void logsoftmax_kernel(u16* __restrict__ pb,
                                                            float* __restrict__ outp)
{
    const int r = blockIdx.x, tid = threadIdx.x, w = tid >> 6, l = tid & 63;
    u16* row = pb + (size_t)r * 30016;
    float* orow = outp + (size_t)r * 30000;
    __shared__ float red[4];

    float m = -1e30f;
    for (int c = tid; c < 3750; c += 256) {
        v8s v = *(const v8s*)(row + c * 8);
#pragma unroll
        for (int i = 0; i < 8; i++) m = fmaxf(m, b2f((u16)v[i]));
    }
#pragma unroll
    for (int off = 32; off; off >>= 1) m = fmaxf(m, __shfl_xor(m, off));
    if (l == 0) red[w] = m;
    __syncthreads();
    m = fmaxf(fmaxf(red[0], red[1]), fmaxf(red[2], red[3]));
    __syncthreads();

    float s = 0.f;
    for (int c = tid; c < 3750; c += 256) {
        v8s v = *(const v8s*)(row + c * 8);
#pragma unroll
        for (int i = 0; i < 8; i++) s += __expf(b2f((u16)v[i]) - m);
    }
#pragma unroll
    for (int off = 32; off; off >>= 1) s += __shfl_xor(s, off);
    if (l == 0) red[w] = s;
    __syncthreads();
    s = red[0] + red[1] + red[2] + red[3];
    const float ls = __logf(s), inv_s = 1.0f / s;

    for (int c = tid; c < 3750; c += 256) {
        v8s v = *(const v8s*)(row + c * 8);
        float4 o0, o1;
        v8s vp;
#pragma unroll
        for (int i = 0; i < 8; i++) {
            float x = b2f((u16)v[i]);
            float oo = x - m - ls;
            if (i < 4) { (&o0.x)[i] = oo; } else { (&o1.x)[i - 4] = oo; }
            vp[i] = (short)f2b(__expf(x - m) * inv_s);
        }
        *(float4*)(orow + c * 8) = o0;
        *(float4*)(orow + c * 8 + 4) = o1;
        *(v8s*)(row + c * 8) = vp;
    }
    if (tid < 16) row[30000 + tid] = 0;
}

// ---------------------------------------------------------------------------
extern "C" void kernel_launch(void* const* d_in, const int* in_sizes, int n_in,
                              void* d_out, int out_size, void* d_ws, size_t ws_size,
                              hipStream_t stream)
{
    const int*   phrase    = (const int*)d_in[0];
    const int*   simp      = (const int*)d_in[1];
    const float* emb_W1    = (const float*)d_in[2];
    const float* emb_b1    = (const float*)d_in[3];
    const float* emb_W2    = (const float*)d_in[4];
    const float* emb_b2    = (const float*)d_in[5];
    const float* enc_Wih   = (const float*)d_in[6];
    const float* enc_Whh   = (const float*)d_in[7];
    const float* enc_bih   = (const float*)d_in[8];
    const float* enc_bhh   = (const float*)d_in[9];
    const float* enc_lin_W = (const float*)d_in[10];
    const float* enc_lin_b = (const float*)d_in[11];
    const float* gen_tab   = (const float*)d_in[12];
    const float* lstm_Wih  = (const float*)d_in[13];
    const float* lstm_Whh  = (const float*)d_in[14];
    const float* lstm_bih  = (const float*)d_in[15];
    const float* lstm_bhh  = (const float*)d_in[16];
    const float* gen_lin_W = (const float*)d_in[17];
    const float* gen_lin_b = (const float*)d_in[18];
    const float* dis_W1    = (const float*)d_in[19];
    const float* dis_b1    = (const float*)d_in[20];
    const float* dis_W2    = (const float*)d_in[21];
    const float* dis_b2    = (const float*)d_in[22];
    const float* dis_Wih   = (const float*)d_in[23];
    const float* dis_Whh   = (const float*)d_in[24];
    const float* dis_bih   = (const float*)d_in[25];
    const float* dis_bhh   = (const float*)d_in[26];
    const float* dis_lin_W = (const float*)d_in[27];
    const float* dis_lin_b = (const float*)d_in[28];
    (void)in_sizes; (void)n_in; (void)out_size; (void)ws_size;

    char* ws = (char*)d_ws;
    unsigned* cnts = (unsigned*)(ws + 1310720);    // 4 barrier counters (64B apart)
    // bf16 weight pool
    u16* pool = (u16*)(ws + 1376256);              // 37011456 elems
    const size_t P_EMB_W2   = 0,        P_ENC_WIH = 262144,   P_ENC_WHH = 1048576;
    const size_t P_ENC_LIN  = 1835008,  P_LSTM_WIH = 2097152, P_LSTM_WHH = 3145728;
    const size_t P_GEN_LIN  = 4194304,  P_DIS_W1  = 19554304, P_DIS_W2  = 34914304;
    const size_t P_DIS_WIH  = 35176448, P_DIS_WHH = 35962880, P_DIS_LIN = 36749312;
    // activations (bf16)
    u16*   e1     = (u16*)(ws + 75399168);
    u16*   e2     = (u16*)(ws + 77496320);
    u16*   d1     = (u16*)(ws + 79593472);
    u16*   d2     = (u16*)(ws + 81690624);
    u16*   dec_in = (u16*)(ws + 83787776);
    u16*   hs     = (u16*)(ws + 85884928);         // 32 x 64KB (per-step LSTM h)
    u16*   g1     = (u16*)(ws + 87982080);
    u16*   g2     = (u16*)(ws + 90079232);
    // xw buffers (f32)
    float* xw_enc = (float*)(ws + 92176384);
    float* xw_d   = (float*)(ws + 104759296);
    float* xw_g   = (float*)(ws + 117342208);
    float* xw_o   = (float*)(ws + 134119424);
    // split-K partial buffer reuses xw_enc..xw_g (dead by the time g1 runs)
    float* skpart = (float*)(ws + 92176384);       // 8 x 2048 x 512 f32 = 33.5 MB
    // probs/logits buffer (bf16, 2048 x 30016)
    u16*   pbuf   = (u16*)(ws + 146702336);        // ends 269647872
    // GRU per-step h buffers overlay the pbuf region (dead during all chains):
    // chain1 setA: pbuf[0 .. 1M elems), setB: pbuf[1M .. 2M); chain3 reuses setA's.
    u16*   gruA   = pbuf;                          // 32 x 32768 u16 = 2 MB
    u16*   gruB   = pbuf + 32 * 32768;             // 32 x 32768 u16 = 2 MB

    float* out_p     = (float*)d_out;              // (32,64,30000)
    float* enc_out_p = (float*)d_out + 61440000;   // (64,512)
    float* enc_sim_p = (float*)d_out + 61472768;   // (64,512)

    // only the barrier counters need zeroing (h0/c0 handled by s==0 skip)
    hipMemsetAsync(ws + 1310720, 0, 256, stream);

    // weight conversion f32 -> bf16 pool
    CvtTab t;
    const float* srcs[12] = { emb_W2, enc_Wih, enc_Whh, enc_lin_W, lstm_Wih, lstm_Whh,
                              gen_lin_W, dis_W1, dis_W2, dis_Wih, dis_Whh, dis_lin_W };
    const size_t offs[12] = { P_EMB_W2, P_ENC_WIH, P_ENC_WHH, P_ENC_LIN, P_LSTM_WIH, P_LSTM_WHH,
                              P_GEN_LIN, P_DIS_W1, P_DIS_W2, P_DIS_WIH, P_DIS_WHH, P_DIS_LIN };
    const int ends[12] = { 128, 512, 896, 1024, 1536, 2048, 9548, 17048, 17176, 17560, 17944, 18072 };
    for (int i = 0; i < 12; i++) { t.src[i] = srcs[i]; t.dst_off[i] = offs[i]; t.blk_end[i] = ends[i]; }
    convert_weights_kernel<<<18072, 256, 0, stream>>>(t, pool);

    // embeddings (one-hot gathers)
    embed_gather_kernel<<<2048, 256, 0, stream>>>(phrase, emb_W1, emb_b1, e1);
    embed_gather_kernel<<<2048, 256, 0, stream>>>(simp, dis_W1, dis_b1, d1);

    // e2/d2 + input-gate GEMMs
    gemm_kernel<0, 1><<<dim3(4, 16), 256, 0, stream>>>(e1, 512, 2048, pool + P_EMB_W2, 512, 512, 512, 512, emb_b2, e2, 512);
    gemm_kernel<0, 1><<<dim3(4, 16), 256, 0, stream>>>(d1, 512, 2048, pool + P_DIS_W2, 512, 512, 512, 512, dis_b2, d2, 512);
    gemm_kernel<1, 0><<<dim3(12, 16), 256, 0, stream>>>(e2, 512, 2048, pool + P_ENC_WIH, 512, 1536, 512, 512, enc_bih, xw_enc, 1536);
    gemm_kernel<1, 0><<<dim3(12, 16), 256, 0, stream>>>(d2, 512, 2048, pool + P_DIS_WIH, 512, 1536, 512, 512, dis_bih, xw_d, 1536);

    // enc GRU + dis GRU: one persistent kernel, 32 steps, fence-free barrier
    {
        GruPC ga = { pool + P_ENC_WHH, enc_bhh, xw_enc, gruA, cnts };
        GruPC gb = { pool + P_DIS_WHH, dis_bhh, xw_d, gruB, cnts + 16 };
        gru_chain_kernel<<<16, 256, 0, stream>>>(ga, gb, 8, 32);
    }
    // final h lives at step-31 buffer of each chain
    gemm_kernel<0, 0><<<dim3(4, 1), 256, 0, stream>>>(gruA + 31 * 32768, 512, 64, pool + P_ENC_LIN, 512, 512, 512, 512, enc_lin_b, dec_in, 512);
    gemm_kernel<1, 0><<<dim3(4, 1), 256, 0, stream>>>(gruB + 31 * 32768, 512, 64, pool + P_DIS_LIN, 512, 512, 512, 512, dis_lin_b, enc_sim_p, 512);

    // generator
    embsim_gather_kernel<<<496, 256, 0, stream>>>(simp, gen_tab, dec_in);
    gemm_kernel<1, 0><<<dim3(16, 16), 256, 0, stream>>>(dec_in, 512, 2048, pool + P_LSTM_WIH, 512, 2048, 512, 512, lstm_bih, xw_g, 2048);
    lstm_chain_kernel<<<8, 256, 0, stream>>>(pool + P_LSTM_WHH, lstm_bhh, xw_g, hs, cnts + 48, 32);

    // vocab projection -> bf16 logits (stride 30016), then log_softmax + probs
    gemm_kernel<0, 0><<<dim3(235, 16), 256, 0, stream>>>(hs, 512, 2048, pool + P_GEN_LIN, 512, 30000, 512, 512, gen_lin_b, pbuf, 30016);
    logsoftmax_kernel<<<2048, 256, 0, stream>>>(pbuf, out_p);

    // discriminator on probs: split-K over K=30000
    gemm_splitk_kernel<<<dim3(4, 16, SK_SPLITS), 256, 0, stream>>>(pbuf, 30016, pool + P_DIS_W1, 30000, 30000, 30016, skpart);
    splitk_reduce_kernel<<<1024, 256, 0, stream>>>(skpart, dis_b1, g1);

    gemm_kernel<0, 1><<<dim3(4, 16), 256, 0, stream>>>(g1, 512, 2048, pool + P_DIS_W2, 512, 512, 512, 512, dis_b2, g2, 512);
    gemm_kernel<1, 0><<<dim3(12, 16), 256, 0, stream>>>(g2, 512, 2048, pool + P_DIS_WIH, 512, 1536, 512, 512, dis_bih, xw_o, 1536);

    // dis GRU on probs: persistent chain (pbuf dead; reuse gruA buffers)
    {
        GruPC gc = { pool + P_DIS_WHH, dis_bhh, xw_o, gruA, cnts + 32 };
        gru_chain_kernel<<<8, 256, 0, stream>>>(gc, gc, 8, 32);
    }
    gemm_kernel<1, 0><<<dim3(4, 1), 256, 0, stream>>>(gruA + 31 * 32768, 512, 64, pool + P_DIS_LIN, 512, 512, 512, 512, dis_lin_b, enc_out_p, 512);
}

// Round 3
// 1576.725 us; speedup vs baseline: 2.0046x; 2.0046x over previous
//
#include <hip/hip_runtime.h>
#include <hip/hip_bf16.h>
#include <math.h>

typedef short v8s __attribute__((ext_vector_type(8)));
typedef float v4f __attribute__((ext_vector_type(4)));
typedef unsigned short u16;

#define THRESH_EPS 1e-6f

__device__ __forceinline__ float b2f(u16 u) {
    union { unsigned int i; float f; } v; v.i = ((unsigned int)u) << 16; return v.f;
}
__device__ __forceinline__ u16 f2b(float f) {
    union { float f; unsigned int i; } v; v.f = f;
    unsigned int x = v.i;
    return (u16)((x + 0x7fffu + ((x >> 16) & 1u)) >> 16);
}
__device__ __forceinline__ float sigm(float x) { return 1.0f / (1.0f + __expf(-x)); }
__device__ __forceinline__ float tanh_(float x) { return 1.0f - 2.0f / (__expf(2.0f * x) + 1.0f); }

// Coherent (write-through) store of one bf16 value: visible at the device
// coherence point once vmcnt retires; no cache-maintenance instructions.
__device__ __forceinline__ void st_coh(u16* p, u16 v) {
    __hip_atomic_store(p, v, __ATOMIC_RELAXED, __HIP_MEMORY_SCOPE_SYSTEM);
}

// Fence-free grid barrier (round-2 protocol, proven correct): h-data already
// coherent via st_coh; vmcnt(0) drains them; counter ops RELAXED.
__device__ __forceinline__ void chain_bar(unsigned* cnt, unsigned target) {
    asm volatile("s_waitcnt vmcnt(0)" ::: "memory");
    __syncthreads();
    if (threadIdx.x == 0) {
        __hip_atomic_fetch_add(cnt, 1u, __ATOMIC_RELAXED, __HIP_MEMORY_SCOPE_AGENT);
        while (__hip_atomic_load(cnt, __ATOMIC_RELAXED, __HIP_MEMORY_SCOPE_AGENT) < target)
            __builtin_amdgcn_s_sleep(2);
    }
    __syncthreads();
}

// ---------------------------------------------------------------------------
// Weight conversion: f32 -> bf16 pool. 12 weight matrices, 2048 elems/block.
// ---------------------------------------------------------------------------
struct CvtTab { const float* src[12]; size_t dst_off[12]; int blk_end[12]; };

__global__ void convert_weights_kernel(CvtTab t, u16* __restrict__ pool)
{
    int b = blockIdx.x;
    int i = 0, start = 0;
    while (b >= t.blk_end[i]) { start = t.blk_end[i]; i++; }
    int local = b - start;
    const float* s = t.src[i] + (size_t)local * 2048 + threadIdx.x * 8;
    u16* d = pool + t.dst_off[i] + (size_t)local * 2048 + threadIdx.x * 8;
    float4 x0 = *(const float4*)s, x1 = *(const float4*)(s + 4);
    v8s o;
    o[0] = (short)f2b(x0.x); o[1] = (short)f2b(x0.y);
    o[2] = (short)f2b(x0.z); o[3] = (short)f2b(x0.w);
    o[4] = (short)f2b(x1.x); o[5] = (short)f2b(x1.y);
    o[6] = (short)f2b(x1.z); o[7] = (short)f2b(x1.w);
    *(v8s*)d = o;
}

// ---------------------------------------------------------------------------
// Generic GEMM: C[M,N] = act(A[M,K] @ W[N,K]^T + bias)  (unchanged)
// ---------------------------------------------------------------------------
template<int OUT_F32, int ACT>
__global__ __launch_bounds__(256, 2) void gemm_kernel(
    const u16* __restrict__ A, int lda, int M,
    const u16* __restrict__ W, int ldw, int N,
    int Kreal, int Kloop,
    const float* __restrict__ bias,
    void* __restrict__ Cout, int ldc)
{
    __shared__ u16 sA[128 * 64];
    __shared__ u16 sB[128 * 64];
    const int tid = threadIdx.x;
    const int m0 = blockIdx.y * 128, n0 = blockIdx.x * 128;
    const int w = tid >> 6, l = tid & 63, lr = l & 15, q = l >> 4;
    const int wm = w & 1, wn = w >> 1;

    v4f acc[4][4];
#pragma unroll
    for (int a = 0; a < 4; a++)
#pragma unroll
        for (int b = 0; b < 4; b++) acc[a][b] = (v4f){0.f, 0.f, 0.f, 0.f};

    for (int kk = 0; kk < Kloop; kk += 64) {
#pragma unroll
        for (int it = 0; it < 4; it++) {
            int cid = it * 256 + tid;
            int r = cid >> 3, j = cid & 7, p = j ^ (r & 7);
            {
                int rm = m0 + r; if (rm > M - 1) rm = M - 1;
                v8s va = *(const v8s*)(A + (size_t)rm * lda + kk + j * 8);
                *(v8s*)(sA + r * 64 + p * 8) = va;
            }
            {
                int rn = n0 + r; if (rn > N - 1) rn = N - 1;
                int kc = kk + j * 8; if (kc + 8 > Kreal) kc = Kreal - 8;
                v8s vb = *(const v8s*)(W + (size_t)rn * ldw + kc);
                *(v8s*)(sB + r * 64 + p * 8) = vb;
            }
        }
        __syncthreads();
#pragma unroll
        for (int ks = 0; ks < 2; ks++) {
            v8s af[4], bfr[4];
#pragma unroll
            for (int mt = 0; mt < 4; mt++) {
                int r = wm * 64 + mt * 16 + lr;
                int j = ks * 4 + q, p = j ^ (r & 7);
                af[mt] = *(const v8s*)(sA + r * 64 + p * 8);
            }
#pragma unroll
            for (int nt = 0; nt < 4; nt++) {
                int r = wn * 64 + nt * 16 + lr;
                int j = ks * 4 + q, p = j ^ (r & 7);
                bfr[nt] = *(const v8s*)(sB + r * 64 + p * 8);
            }
#pragma unroll
            for (int mt = 0; mt < 4; mt++)
#pragma unroll
                for (int nt = 0; nt < 4; nt++)
                    acc[mt][nt] = __builtin_amdgcn_mfma_f32_16x16x32_bf16(
                        af[mt], bfr[nt], acc[mt][nt], 0, 0, 0);
        }
        __syncthreads();
    }

#pragma unroll
    for (int nt = 0; nt < 4; nt++) {
        int n = n0 + wn * 64 + nt * 16 + lr;
        if (n >= N) continue;
        float bv = bias[n];
#pragma unroll
        for (int mt = 0; mt < 4; mt++) {
#pragma unroll
            for (int i = 0; i < 4; i++) {
                int m = m0 + wm * 64 + mt * 16 + q * 4 + i;
                if (m >= M) continue;
                float vout = acc[mt][nt][i] + bv;
                if (ACT == 1) vout = (vout > THRESH_EPS) ? vout : 0.0f;
                if (OUT_F32) ((float*)Cout)[(size_t)m * ldc + n] = vout;
                else         ((u16*)Cout)[(size_t)m * ldc + n] = f2b(vout);
            }
        }
    }
}

// ---------------------------------------------------------------------------
// Split-K GEMM for g1 (unchanged)
// ---------------------------------------------------------------------------
#define SK_CHUNK 3776
#define SK_SPLITS 8

__global__ __launch_bounds__(256, 2) void gemm_splitk_kernel(
    const u16* __restrict__ A, int lda,
    const u16* __restrict__ W, int ldw,
    int Kreal, int Ktot,
    float* __restrict__ Cpart)
{
    __shared__ u16 sA[128 * 64];
    __shared__ u16 sB[128 * 64];
    const int tid = threadIdx.x;
    const int m0 = blockIdx.y * 128, n0 = blockIdx.x * 128;
    const int z = blockIdx.z;
    const int kstart = z * SK_CHUNK;
    int Kl = Ktot - kstart; if (Kl > SK_CHUNK) Kl = SK_CHUNK;
    const int w = tid >> 6, l = tid & 63, lr = l & 15, q = l >> 4;
    const int wm = w & 1, wn = w >> 1;

    v4f acc[4][4];
#pragma unroll
    for (int a = 0; a < 4; a++)
#pragma unroll
        for (int b = 0; b < 4; b++) acc[a][b] = (v4f){0.f, 0.f, 0.f, 0.f};

    for (int kk = 0; kk < Kl; kk += 64) {
#pragma unroll
        for (int it = 0; it < 4; it++) {
            int cid = it * 256 + tid;
            int r = cid >> 3, j = cid & 7, p = j ^ (r & 7);
            {
                v8s va = *(const v8s*)(A + (size_t)(m0 + r) * lda + kstart + kk + j * 8);
                *(v8s*)(sA + r * 64 + p * 8) = va;
            }
            {
                int kc = kstart + kk + j * 8; if (kc + 8 > Kreal) kc = Kreal - 8;
                v8s vb = *(const v8s*)(W + (size_t)(n0 + r) * ldw + kc);
                *(v8s*)(sB + r * 64 + p * 8) = vb;
            }
        }
        __syncthreads();
#pragma unroll
        for (int ks = 0; ks < 2; ks++) {
            v8s af[4], bfr[4];
#pragma unroll
            for (int mt = 0; mt < 4; mt++) {
                int r = wm * 64 + mt * 16 + lr;
                int j = ks * 4 + q, p = j ^ (r & 7);
                af[mt] = *(const v8s*)(sA + r * 64 + p * 8);
            }
#pragma unroll
            for (int nt = 0; nt < 4; nt++) {
                int r = wn * 64 + nt * 16 + lr;
                int j = ks * 4 + q, p = j ^ (r & 7);
                bfr[nt] = *(const v8s*)(sB + r * 64 + p * 8);
            }
#pragma unroll
            for (int mt = 0; mt < 4; mt++)
#pragma unroll
                for (int nt = 0; nt < 4; nt++)
                    acc[mt][nt] = __builtin_amdgcn_mfma_f32_16x16x32_bf16(
                        af[mt], bfr[nt], acc[mt][nt], 0, 0, 0);
        }
        __syncthreads();
    }

    float* out = Cpart + (size_t)z * 1048576;
#pragma unroll
    for (int nt = 0; nt < 4; nt++) {
        int n = n0 + wn * 64 + nt * 16 + lr;
#pragma unroll
        for (int mt = 0; mt < 4; mt++) {
#pragma unroll
            for (int i = 0; i < 4; i++) {
                int m = m0 + wm * 64 + mt * 16 + q * 4 + i;
                out[(size_t)m * 512 + n] = acc[mt][nt][i];
            }
        }
    }
}

// Reduce 8 f32 partials -> thresh(+bias) -> bf16 g1 (2048 x 512)
__global__ void splitk_reduce_kernel(const float* __restrict__ part,
                                     const float* __restrict__ bias,
                                     u16* __restrict__ out)
{
    int t = blockIdx.x * 256 + threadIdx.x;
    size_t base = (size_t)t * 4;
    float4 s = *(const float4*)(part + base);
#pragma unroll
    for (int zz = 1; zz < SK_SPLITS; zz++) {
        float4 p = *(const float4*)(part + (size_t)zz * 1048576 + base);
        s.x += p.x; s.y += p.y; s.z += p.z; s.w += p.w;
    }
    int n = (int)(base & 511);
    float4 bv = *(const float4*)(bias + n);
    float o[4] = { s.x + bv.x, s.y + bv.y, s.z + bv.z, s.w + bv.w };
    u16 r0 = f2b(o[0] > THRESH_EPS ? o[0] : 0.f);
    u16 r1 = f2b(o[1] > THRESH_EPS ? o[1] : 0.f);
    u16 r2 = f2b(o[2] > THRESH_EPS ? o[2] : 0.f);
    u16 r3 = f2b(o[3] > THRESH_EPS ? o[3] : 0.f);
    out[base + 0] = r0; out[base + 1] = r1; out[base + 2] = r2; out[base + 3] = r3;
}

// ---------------------------------------------------------------------------
// Persistent GRU chain v3. 32 blocks/set x 16 cols. Whh slice (48 KB) staged
// to LDS once. wave = batch-quarter: each wave computes ALL 3 gates for its
// 16 rows x 16 cols -> epilogue fully in registers (no exchange). xw
// prefetched at step top. h exchanged via per-step fresh buffers, coherent
// write-through stores, relaxed grid barrier (32 blocks per set).
// ---------------------------------------------------------------------------
struct GruPC {
    const u16* Whh; const float* bhh; const float* xw; // xw: (32,64,1536) f32
    u16* hb;                                            // 32 step buffers, 64x512 bf16
    unsigned* cnt;
};

__global__ __launch_bounds__(256, 1) void gru_chain_kernel(GruPC s0, GruPC s1, int nsteps)
{
    __shared__ u16 bsh[3 * 16 * 64 * 8];   // 48 KB: [g][kk][lane] -> 8 u16
    const GruPC S = ((int)blockIdx.x < 32) ? s0 : s1;
    const int cb = ((int)blockIdx.x & 31) * 16;
    const int tid = threadIdx.x, w = tid >> 6, l = tid & 63, lr = l & 15, q = l >> 4;
    const int col = cb + lr;

    // stage Whh slice: 3072 fragments, 12 per thread
#pragma unroll
    for (int it = 0; it < 12; it++) {
        int id = it * 256 + tid;
        int g = id >> 10, kk = (id >> 6) & 15, ll = id & 63;
        int lrow = g * 512 + cb + (ll & 15);
        int kcol = kk * 32 + (ll >> 4) * 8;
        v8s v = *(const v8s*)(S.Whh + (size_t)lrow * 512 + kcol);
        *(v8s*)(bsh + (size_t)id * 8) = v;
    }
    __syncthreads();

    const float br = S.bhh[col], bz = S.bhh[512 + col], bn = S.bhh[1024 + col];
    float hreg[4] = {0.f, 0.f, 0.f, 0.f};   // rows w*16 + q*4 + i, col

    for (int s = 0; s < nsteps; s++) {
        // prefetch xw (independent of hin -> overlaps MFMA phase)
        const float* xws = S.xw + (size_t)s * 98304;
        float xf[3][4];
#pragma unroll
        for (int i = 0; i < 4; i++) {
            int row = w * 16 + q * 4 + i;
#pragma unroll
            for (int g = 0; g < 3; g++)
                xf[g][i] = xws[row * 1536 + g * 512 + col];
        }

        v4f acc[3];
#pragma unroll
        for (int g = 0; g < 3; g++) acc[g] = (v4f){0.f, 0.f, 0.f, 0.f};

        if (s > 0) {
            const u16* hin = S.hb + (size_t)(s - 1) * 32768;
#pragma unroll
            for (int kk = 0; kk < 16; kk++) {
                v8s a = *(const v8s*)(hin + (w * 16 + lr) * 512 + kk * 32 + q * 8);
#pragma unroll
                for (int g = 0; g < 3; g++) {
                    v8s b = *(const v8s*)(bsh + ((size_t)(g * 16 + kk) * 64 + l) * 8);
                    acc[g] = __builtin_amdgcn_mfma_f32_16x16x32_bf16(a, b, acc[g], 0, 0, 0);
                }
            }
        }

        u16* hout = S.hb + (size_t)s * 32768;
#pragma unroll
        for (int i = 0; i < 4; i++) {
            int row = w * 16 + q * 4 + i;
            float r = sigm(xf[0][i] + acc[0][i] + br);
            float z = sigm(xf[1][i] + acc[1][i] + bz);
            float n = tanh_(xf[2][i] + r * (acc[2][i] + bn));
            float hn = (1.f - z) * n + z * hreg[i];
            hreg[i] = hn;
            st_coh(hout + row * 512 + col, f2b(hn));
        }
        chain_bar(S.cnt, (unsigned)((s + 1) * 32));
    }
}

// ---------------------------------------------------------------------------
// Persistent LSTM chain v3. 32 blocks x 16 cols; Whh slice = 64 KB LDS;
// wave = batch-quarter (all 4 gates in-lane); c in registers.
// ---------------------------------------------------------------------------
__global__ __launch_bounds__(256, 1) void lstm_chain_kernel(
    const u16* __restrict__ Whh, const float* __restrict__ bhh,
    const float* __restrict__ xw_all, u16* __restrict__ hs,
    unsigned* cnt, int nsteps)
{
    __shared__ u16 bsh[4 * 16 * 64 * 8];   // 64 KB
    const int cb = (int)blockIdx.x * 16;
    const int tid = threadIdx.x, w = tid >> 6, l = tid & 63, lr = l & 15, q = l >> 4;
    const int col = cb + lr;

    // stage Whh slice: 4096 fragments, 16 per thread
#pragma unroll
    for (int it = 0; it < 16; it++) {
        int id = it * 256 + tid;
        int g = id >> 10, kk = (id >> 6) & 15, ll = id & 63;
        int lrow = g * 512 + cb + (ll & 15);
        int kcol = kk * 32 + (ll >> 4) * 8;
        v8s v = *(const v8s*)(Whh + (size_t)lrow * 512 + kcol);
        *(v8s*)(bsh + (size_t)id * 8) = v;
    }
    __syncthreads();

    const float b0 = bhh[col], b1 = bhh[512 + col], b2_ = bhh[1024 + col], b3 = bhh[1536 + col];
    float creg[4] = {0.f, 0.f, 0.f, 0.f};

    for (int s = 0; s < nsteps; s++) {
        const float* xws = xw_all + (size_t)s * 131072;
        float xf[4][4];
#pragma unroll
        for (int i = 0; i < 4; i++) {
            int row = w * 16 + q * 4 + i;
#pragma unroll
            for (int g = 0; g < 4; g++)
                xf[g][i] = xws[row * 2048 + g * 512 + col];
        }

        v4f acc[4];
#pragma unroll
        for (int g = 0; g < 4; g++) acc[g] = (v4f){0.f, 0.f, 0.f, 0.f};

        if (s > 0) {
            const u16* hin = hs + (size_t)(s - 1) * 32768;
#pragma unroll
            for (int kk = 0; kk < 16; kk++) {
                v8s a = *(const v8s*)(hin + (w * 16 + lr) * 512 + kk * 32 + q * 8);
#pragma unroll
                for (int g = 0; g < 4; g++) {
                    v8s b = *(const v8s*)(bsh + ((size_t)(g * 16 + kk) * 64 + l) * 8);
                    acc[g] = __builtin_amdgcn_mfma_f32_16x16x32_bf16(a, b, acc[g], 0, 0, 0);
                }
            }
        }

        u16* hout = hs + (size_t)s * 32768;
#pragma unroll
        for (int i = 0; i < 4; i++) {
            int row = w * 16 + q * 4 + i;
            float gi = sigm(xf[0][i] + acc[0][i] + b0);
            float gf = sigm(xf[1][i] + acc[1][i] + b1);
            float gg = tanh_(xf[2][i] + acc[2][i] + b2_);
            float go = sigm(xf[3][i] + acc[3][i] + b3);
            float cn = gf * creg[i] + gi * gg;
            creg[i] = cn;
            st_coh(hout + row * 512 + col, f2b(go * tanh_(cn)));
        }
        chain_bar(cnt, (unsigned)((s + 1) * 32));
    }
}

// ---------------------------------------------------------------------------
// e1/d1: out[row, j] = thresh(W1[j, idx[row]] + b1[j]); rows = S*B = 2048
// ---------------------------------------------------------------------------
__global__ void embed_gather_kernel(const int* __restrict__ idx, const float* __restrict__ W1,
                                    const float* __restrict__ b1, u16* __restrict__ out)
{
    const int row = blockIdx.x;
    const int p = idx[row];
    for (int j = threadIdx.x; j < 512; j += 256) {
        float v = W1[(size_t)j * 30000 + p] + b1[j];
        out[(size_t)row * 512 + j] = f2b(v > THRESH_EPS ? v : 0.f);
    }
}

// dec_in[64 + row, :] = bf16(gen_emb_tab[sim[row], :]), row in [0, 1984)
__global__ void embsim_gather_kernel(const int* __restrict__ sim, const float* __restrict__ tab,
                                     u16* __restrict__ dec_in)
{
    int cid = blockIdx.x * 256 + threadIdx.x;
    int row = cid >> 6, c8 = cid & 63;
    if (row >= 1984) return;
    int p = sim[row];
    const float* s = tab + (size_t)p * 512 + c8 * 8;
    float4 x0 = *(const float4*)s, x1 = *(const float4*)(s + 4);
    v8s o;
    o[0] = (short)f2b(x0.x); o[1] = (short)f2b(x0.y);
    o[2] = (short)f2b(x0.z); o[3] = (short)f2b(x0.w);
    o[4] = (short)f2b(x1.x); o[5] = (short)f2b(x1.y);
    o[6] = (short)f2b(x1.z); o[7] = (short)f2b(x1.w);
    *(v8s*)(dec_in + (size_t)(64 + row) * 512 + c8 * 8) = o;
}

// ---------------------------------------------------------------------------
// log_softmax per row of 30000 bf16 logits (stride 30016 in pbuf).
// ---------------------------------------------------------------------------
__global__ __launch_bounds__(256, 2) void logsoftmax_kernel(u16* __restrict__ pb,
                                                            float* __restrict__ outp)
{
    const int r = blockIdx.x, tid = threadIdx.x, w = tid >> 6, l = tid & 63;
    u16* row = pb + (size_t)r * 30016;
    float* orow = outp + (size_t)r * 30000;
    __shared__ float red[4];

    float m = -1e30f;
    for (int c = tid; c < 3750; c += 256) {
        v8s v = *(const v8s*)(row + c * 8);
#pragma unroll
        for (int i = 0; i < 8; i++) m = fmaxf(m, b2f((u16)v[i]));
    }
#pragma unroll
    for (int off = 32; off; off >>= 1) m = fmaxf(m, __shfl_xor(m, off));
    if (l == 0) red[w] = m;
    __syncthreads();
    m = fmaxf(fmaxf(red[0], red[1]), fmaxf(red[2], red[3]));
    __syncthreads();

    float s = 0.f;
    for (int c = tid; c < 3750; c += 256) {
        v8s v = *(const v8s*)(row + c * 8);
#pragma unroll
        for (int i = 0; i < 8; i++) s += __expf(b2f((u16)v[i]) - m);
    }
#pragma unroll
    for (int off = 32; off; off >>= 1) s += __shfl_xor(s, off);
    if (l == 0) red[w] = s;
    __syncthreads();
    s = red[0] + red[1] + red[2] + red[3];
    const float ls = __logf(s), inv_s = 1.0f / s;

    for (int c = tid; c < 3750; c += 256) {
        v8s v = *(const v8s*)(row + c * 8);
        float4 o0, o1;
        v8s vp;
#pragma unroll
        for (int i = 0; i < 8; i++) {
            float x = b2f((u16)v[i]);
            float oo = x - m - ls;
            if (i < 4) { (&o0.x)[i] = oo; } else { (&o1.x)[i - 4] = oo; }
            vp[i] = (short)f2b(__expf(x - m) * inv_s);
        }
        *(float4*)(orow + c * 8) = o0;
        *(float4*)(orow + c * 8 + 4) = o1;
        *(v8s*)(row + c * 8) = vp;
    }
    if (tid < 16) row[30000 + tid] = 0;
}

// ---------------------------------------------------------------------------
extern "C" void kernel_launch(void* const* d_in, const int* in_sizes, int n_in,
                              void* d_out, int out_size, void* d_ws, size_t ws_size,
                              hipStream_t stream)
{
    const int*   phrase    = (const int*)d_in[0];
    const int*   simp      = (const int*)d_in[1];
    const float* emb_W1    = (const float*)d_in[2];
    const float* emb_b1    = (const float*)d_in[3];
    const float* emb_W2    = (const float*)d_in[4];
    const float* emb_b2    = (const float*)d_in[5];
    const float* enc_Wih   = (const float*)d_in[6];
    const float* enc_Whh   = (const float*)d_in[7];
    const float* enc_bih   = (const float*)d_in[8];
    const float* enc_bhh   = (const float*)d_in[9];
    const float* enc_lin_W = (const float*)d_in[10];
    const float* enc_lin_b = (const float*)d_in[11];
    const float* gen_tab   = (const float*)d_in[12];
    const float* lstm_Wih  = (const float*)d_in[13];
    const float* lstm_Whh  = (const float*)d_in[14];
    const float* lstm_bih  = (const float*)d_in[15];
    const float* lstm_bhh  = (const float*)d_in[16];
    const float* gen_lin_W = (const float*)d_in[17];
    const float* gen_lin_b = (const float*)d_in[18];
    const float* dis_W1    = (const float*)d_in[19];
    const float* dis_b1    = (const float*)d_in[20];
    const float* dis_W2    = (const float*)d_in[21];
    const float* dis_b2    = (const float*)d_in[22];
    const float* dis_Wih   = (const float*)d_in[23];
    const float* dis_Whh   = (const float*)d_in[24];
    const float* dis_bih   = (const float*)d_in[25];
    const float* dis_bhh   = (const float*)d_in[26];
    const float* dis_lin_W = (const float*)d_in[27];
    const float* dis_lin_b = (const float*)d_in[28];
    (void)in_sizes; (void)n_in; (void)out_size; (void)ws_size;

    char* ws = (char*)d_ws;
    unsigned* cnts = (unsigned*)(ws + 1310720);    // 4 barrier counters (64B apart)
    // bf16 weight pool
    u16* pool = (u16*)(ws + 1376256);              // 37011456 elems
    const size_t P_EMB_W2   = 0,        P_ENC_WIH = 262144,   P_ENC_WHH = 1048576;
    const size_t P_ENC_LIN  = 1835008,  P_LSTM_WIH = 2097152, P_LSTM_WHH = 3145728;
    const size_t P_GEN_LIN  = 4194304,  P_DIS_W1  = 19554304, P_DIS_W2  = 34914304;
    const size_t P_DIS_WIH  = 35176448, P_DIS_WHH = 35962880, P_DIS_LIN = 36749312;
    // activations (bf16)
    u16*   e1     = (u16*)(ws + 75399168);
    u16*   e2     = (u16*)(ws + 77496320);
    u16*   d1     = (u16*)(ws + 79593472);
    u16*   d2     = (u16*)(ws + 81690624);
    u16*   dec_in = (u16*)(ws + 83787776);
    u16*   hs     = (u16*)(ws + 85884928);         // 32 x 64KB (per-step LSTM h)
    u16*   g1     = (u16*)(ws + 87982080);
    u16*   g2     = (u16*)(ws + 90079232);
    // xw buffers (f32)
    float* xw_enc = (float*)(ws + 92176384);
    float* xw_d   = (float*)(ws + 104759296);
    float* xw_g   = (float*)(ws + 117342208);
    float* xw_o   = (float*)(ws + 134119424);
    // split-K partial buffer reuses xw_enc..xw_g (dead by the time g1 runs)
    float* skpart = (float*)(ws + 92176384);       // 8 x 2048 x 512 f32 = 33.5 MB
    // probs/logits buffer (bf16, 2048 x 30016)
    u16*   pbuf   = (u16*)(ws + 146702336);        // ends 269647872
    // GRU per-step h buffers overlay the pbuf region (dead during all chains)
    u16*   gruA   = pbuf;                          // 32 x 32768 u16 = 2 MB
    u16*   gruB   = pbuf + 32 * 32768;             // 32 x 32768 u16 = 2 MB

    float* out_p     = (float*)d_out;              // (32,64,30000)
    float* enc_out_p = (float*)d_out + 61440000;   // (64,512)
    float* enc_sim_p = (float*)d_out + 61472768;   // (64,512)

    // only the barrier counters need zeroing (h0/c0 handled by s==0 skip)
    hipMemsetAsync(ws + 1310720, 0, 256, stream);

    // weight conversion f32 -> bf16 pool
    CvtTab t;
    const float* srcs[12] = { emb_W2, enc_Wih, enc_Whh, enc_lin_W, lstm_Wih, lstm_Whh,
                              gen_lin_W, dis_W1, dis_W2, dis_Wih, dis_Whh, dis_lin_W };
    const size_t offs[12] = { P_EMB_W2, P_ENC_WIH, P_ENC_WHH, P_ENC_LIN, P_LSTM_WIH, P_LSTM_WHH,
                              P_GEN_LIN, P_DIS_W1, P_DIS_W2, P_DIS_WIH, P_DIS_WHH, P_DIS_LIN };
    const int ends[12] = { 128, 512, 896, 1024, 1536, 2048, 9548, 17048, 17176, 17560, 17944, 18072 };
    for (int i = 0; i < 12; i++) { t.src[i] = srcs[i]; t.dst_off[i] = offs[i]; t.blk_end[i] = ends[i]; }
    convert_weights_kernel<<<18072, 256, 0, stream>>>(t, pool);

    // embeddings (one-hot gathers)
    embed_gather_kernel<<<2048, 256, 0, stream>>>(phrase, emb_W1, emb_b1, e1);
    embed_gather_kernel<<<2048, 256, 0, stream>>>(simp, dis_W1, dis_b1, d1);

    // e2/d2 + input-gate GEMMs
    gemm_kernel<0, 1><<<dim3(4, 16), 256, 0, stream>>>(e1, 512, 2048, pool + P_EMB_W2, 512, 512, 512, 512, emb_b2, e2, 512);
    gemm_kernel<0, 1><<<dim3(4, 16), 256, 0, stream>>>(d1, 512, 2048, pool + P_DIS_W2, 512, 512, 512, 512, dis_b2, d2, 512);
    gemm_kernel<1, 0><<<dim3(12, 16), 256, 0, stream>>>(e2, 512, 2048, pool + P_ENC_WIH, 512, 1536, 512, 512, enc_bih, xw_enc, 1536);
    gemm_kernel<1, 0><<<dim3(12, 16), 256, 0, stream>>>(d2, 512, 2048, pool + P_DIS_WIH, 512, 1536, 512, 512, dis_bih, xw_d, 1536);

    // enc GRU + dis GRU: one persistent kernel (2 sets x 32 blocks)
    {
        GruPC ga = { pool + P_ENC_WHH, enc_bhh, xw_enc, gruA, cnts };
        GruPC gb = { pool + P_DIS_WHH, dis_bhh, xw_d, gruB, cnts + 16 };
        gru_chain_kernel<<<64, 256, 0, stream>>>(ga, gb, 32);
    }
    // final h lives at step-31 buffer of each chain
    gemm_kernel<0, 0><<<dim3(4, 1), 256, 0, stream>>>(gruA + 31 * 32768, 512, 64, pool + P_ENC_LIN, 512, 512, 512, 512, enc_lin_b, dec_in, 512);
    gemm_kernel<1, 0><<<dim3(4, 1), 256, 0, stream>>>(gruB + 31 * 32768, 512, 64, pool + P_DIS_LIN, 512, 512, 512, 512, dis_lin_b, enc_sim_p, 512);

    // generator
    embsim_gather_kernel<<<496, 256, 0, stream>>>(simp, gen_tab, dec_in);
    gemm_kernel<1, 0><<<dim3(16, 16), 256, 0, stream>>>(dec_in, 512, 2048, pool + P_LSTM_WIH, 512, 2048, 512, 512, lstm_bih, xw_g, 2048);
    lstm_chain_kernel<<<32, 256, 0, stream>>>(pool + P_LSTM_WHH, lstm_bhh, xw_g, hs, cnts + 32, 32);

    // vocab projection -> bf16 logits (stride 30016), then log_softmax + probs
    gemm_kernel<0, 0><<<dim3(235, 16), 256, 0, stream>>>(hs, 512, 2048, pool + P_GEN_LIN, 512, 30000, 512, 512, gen_lin_b, pbuf, 30016);
    logsoftmax_kernel<<<2048, 256, 0, stream>>>(pbuf, out_p);

    // discriminator on probs: split-K over K=30000
    gemm_splitk_kernel<<<dim3(4, 16, SK_SPLITS), 256, 0, stream>>>(pbuf, 30016, pool + P_DIS_W1, 30000, 30000, 30016, skpart);
    splitk_reduce_kernel<<<1024, 256, 0, stream>>>(skpart, dis_b1, g1);

    gemm_kernel<0, 1><<<dim3(4, 16), 256, 0, stream>>>(g1, 512, 2048, pool + P_DIS_W2, 512, 512, 512, 512, dis_b2, g2, 512);
    gemm_kernel<1, 0><<<dim3(12, 16), 256, 0, stream>>>(g2, 512, 2048, pool + P_DIS_WIH, 512, 1536, 512, 512, dis_bih, xw_o, 1536);

    // dis GRU on probs: persistent chain (pbuf dead; reuse gruA buffers)
    {
        GruPC gc = { pool + P_DIS_WHH, dis_bhh, xw_o, gruA, cnts + 48 };
        gru_chain_kernel<<<32, 256, 0, stream>>>(gc, gc, 32);
    }
    gemm_kernel<1, 0><<<dim3(4, 1), 256, 0, stream>>>(gruA + 31 * 32768, 512, 64, pool + P_DIS_LIN, 512, 512, 512, 512, dis_lin_b, enc_out_p, 512);
}